// Round 13
// baseline (67.032 us; speedup 1.0000x reference)
//
#include <hip/hip_runtime.h>

// log sigma_{63,64} of exp(x) along classes: x (2048,10000) f32 -> out (2,2048) f32.
// TWO-KERNEL SPLIT (round 13): round-12's single kernel serialized load (~13us)
// and compute (~15us) per generation. Kernel 1 = leaf phase only (low VGPR, no
// tree LDS, 6 blocks/CU) -> HBM-bound streaming; writes per-sample quad polys
// (64 x 12 coeffs, tilted+normalized), 4 wave-S logs, tau to ws (6.4 MB).
// Kernel 2 = stages ws -> W2 LDS layout, then round-12's verified L3..L8 tree.
// Fallback to the round-12 monolith if ws_size is ever too small.

#define NS 2048
#define NC 10000
#define KSEL 64

// per-sample ws layout (floats): [0..767] 64 quads x 12 coeffs; [768..771] wave S; [772] tau
#define WSS 784

// LDS arena float offsets/strides: row = [lowpad z | coeffs | top z]
#define OW2 0      // 64 rows x 32  : [12z | 12 (deg<=11) | 8z]
#define OW3 2048   // 32 rows x 44  : [20z | 17 (deg<=16) | 7z]
#define OW4 3456   // 16 rows x 60  : [24z | 21 (deg<=20) | 15z]
#define OW5 4416   //  8 rows x 84  : [36z | 33 (deg<=32) | 15z]
#define OW6 5088   //  4 rows x 116 : [48z | 45 (deg<=44) | 23z]
#define OW7 5552   //  2 rows x 68  : [65 (deg<=64) | 3z]
#define LDSF 5688  // total floats (= 1422 float4)

__device__ __forceinline__ float4 ld4(const float* p) { return *(const float4*)p; }
__device__ __forceinline__ void st4(float* p, float a, float b, float c, float d) {
  *(float4*)p = make_float4(a, b, c, d);
}

// 16-FMA sliding block: acc_q += a4[k] * b_{j0+q-(i0+k)} with bh=B[j0-i0..+3], bl=B[j0-i0-4..-1]
#define CONV4(a4, bl, bh)                                                               \
  a0 = fmaf(a4.x, bh.x, a0); a1 = fmaf(a4.x, bh.y, a1); a2 = fmaf(a4.x, bh.z, a2); a3 = fmaf(a4.x, bh.w, a3); \
  a0 = fmaf(a4.y, bl.w, a0); a1 = fmaf(a4.y, bh.x, a1); a2 = fmaf(a4.y, bh.y, a2); a3 = fmaf(a4.y, bh.z, a3); \
  a0 = fmaf(a4.z, bl.z, a0); a1 = fmaf(a4.z, bl.w, a1); a2 = fmaf(a4.z, bh.x, a2); a3 = fmaf(a4.z, bh.y, a3); \
  a0 = fmaf(a4.w, bl.y, a0); a1 = fmaf(a4.w, bl.z, a1); a2 = fmaf(a4.w, bl.w, a2); a3 = fmaf(a4.w, bh.x, a3)

// Shared leaf phase: loads, exp, tilt, normalize, RL1/RL2. Emits g0..g11 (quad poly),
// per-wave S (lane0), tau. Template over destination handled by callers.
#define LEAF_PHASE                                                                       \
  const float4* xv = (const float4*)(x + (size_t)s * NC);                                \
  float4 buf[10];                                                                        \
  _Pragma("unroll")                                                                      \
  for (int it = 0; it < 9; ++it) buf[it] = xv[t + it * 256];                             \
  buf[9] = make_float4(-1e30f, -1e30f, -1e30f, -1e30f);                                  \
  if (t < 196) buf[9] = xv[2304 + t];                                                    \
  float c0 = 1.f, c1 = 0.f, c2 = 0.f, c3 = 0.f, c4 = 0.f, c5 = 0.f, c6 = 0.f;            \
  float sw = 0.f;                                                                        \
  _Pragma("unroll")                                                                      \
  for (int it = 0; it < 10; ++it) {                                                      \
    const float4 v = buf[it];                                                            \
    _Pragma("unroll")                                                                    \
    for (int q = 0; q < 4; ++q) {                                                        \
      const float xval = q == 0 ? v.x : q == 1 ? v.y : q == 2 ? v.z : v.w;               \
      const float w = __expf(xval);                                                      \
      sw += w;                                                                           \
      c6 = fmaf(w, c5, c6); c5 = fmaf(w, c4, c5); c4 = fmaf(w, c3, c4);                  \
      c3 = fmaf(w, c2, c3); c2 = fmaf(w, c1, c2); c1 = fmaf(w, c0, c1);                  \
    }                                                                                    \
  }                                                                                      \
  _Pragma("unroll")                                                                      \
  for (int m = 1; m < 64; m <<= 1) sw += __shfl_xor(sw, m);                              \
  if ((t & 63) == 0) red[wv] = sw;                                                       \
  __syncthreads();                                                                       \
  const float wsum = red[0] + red[1] + red[2] + red[3];                                  \
  const float tau = __logf(wsum * ((float)(NC - KSEL) / ((float)KSEL * (float)NC)));     \
  {                                                                                      \
    const float f1 = __expf(-tau);                                                       \
    const float f2 = f1 * f1, f3 = f2 * f1, f4v = f2 * f2, f5 = f4v * f1, f6 = f4v * f2; \
    c1 *= f1; c2 *= f2; c3 *= f3; c4 *= f4v; c5 *= f5; c6 *= f6;                         \
  }                                                                                      \
  float Sr;                                                                              \
  {                                                                                      \
    const float mx = fmaxf(fmaxf(fmaxf(c0, c1), fmaxf(c2, c3)), fmaxf(fmaxf(c4, c5), c6)); \
    const float invm = 1.f / mx;                                                         \
    c0 *= invm; c1 *= invm; c2 *= invm; c3 *= invm; c4 *= invm; c5 *= invm; c6 *= invm;  \
    Sr = __logf(mx);                                                                     \
    _Pragma("unroll")                                                                    \
    for (int m = 1; m < 64; m <<= 1) Sr += __shfl_xor(Sr, m);                            \
  }                                                                                      \
  const float q0 = __shfl_xor(c0, 1), q1 = __shfl_xor(c1, 1), q2 = __shfl_xor(c2, 1),    \
              q3 = __shfl_xor(c3, 1), q4 = __shfl_xor(c4, 1), q5 = __shfl_xor(c5, 1),    \
              q6 = __shfl_xor(c6, 1);                                                    \
  const float e0 = c0 * q0;                                                              \
  const float e1 = fmaf(c1, q0, c0 * q1);                                                \
  const float e2 = fmaf(c2, q0, fmaf(c1, q1, c0 * q2));                                  \
  const float e3 = fmaf(c3, q0, fmaf(c2, q1, fmaf(c1, q2, c0 * q3)));                    \
  const float e4 = fmaf(c4, q0, fmaf(c3, q1, fmaf(c2, q2, fmaf(c1, q3, c0 * q4))));      \
  const float e5 = fmaf(c5, q0, fmaf(c4, q1, fmaf(c3, q2, fmaf(c2, q3, fmaf(c1, q4, c0 * q5))))); \
  const float e6 = fmaf(c6, q0, fmaf(c5, q1, fmaf(c4, q2, fmaf(c3, q3, fmaf(c2, q4, fmaf(c1, q5, c0 * q6)))))); \
  const float e7 = fmaf(c6, q1, fmaf(c5, q2, fmaf(c4, q3, fmaf(c3, q4, fmaf(c2, q5, c1 * q6))))); \
  const float f0 = __shfl_xor(e0, 2), f1 = __shfl_xor(e1, 2), f2 = __shfl_xor(e2, 2),    \
              f3 = __shfl_xor(e3, 2), f4 = __shfl_xor(e4, 2), f5 = __shfl_xor(e5, 2),    \
              f6 = __shfl_xor(e6, 2), f7 = __shfl_xor(e7, 2);                            \
  const float g0 = e0 * f0;                                                              \
  const float g1 = fmaf(e1, f0, e0 * f1);                                                \
  const float g2 = fmaf(e2, f0, fmaf(e1, f1, e0 * f2));                                  \
  const float g3 = fmaf(e3, f0, fmaf(e2, f1, fmaf(e1, f2, e0 * f3)));                    \
  const float g4 = fmaf(e4, f0, fmaf(e3, f1, fmaf(e2, f2, fmaf(e1, f3, e0 * f4))));      \
  const float g5 = fmaf(e5, f0, fmaf(e4, f1, fmaf(e3, f2, fmaf(e2, f3, fmaf(e1, f4, e0 * f5))))); \
  const float g6 = fmaf(e6, f0, fmaf(e5, f1, fmaf(e4, f2, fmaf(e3, f3, fmaf(e2, f4, fmaf(e1, f5, e0 * f6)))))); \
  const float g7 = fmaf(e7, f0, fmaf(e6, f1, fmaf(e5, f2, fmaf(e4, f3, fmaf(e3, f4, fmaf(e2, f5, fmaf(e1, f6, e0 * f7))))))); \
  const float g8 = fmaf(e7, f1, fmaf(e6, f2, fmaf(e5, f3, fmaf(e4, f4, fmaf(e3, f5, fmaf(e2, f6, e1 * f7)))))); \
  const float g9 = fmaf(e7, f2, fmaf(e6, f3, fmaf(e5, f4, fmaf(e4, f5, fmaf(e3, f6, e2 * f7))))); \
  const float g10 = fmaf(e7, f3, fmaf(e6, f4, fmaf(e5, f5, fmaf(e4, f6, e3 * f7))));     \
  const float g11 = fmaf(e7, f4, fmaf(e6, f5, fmaf(e5, f6, e4 * f7)));

// The verified L3..L8 tree (round 12). Requires: LW staged (W2 payload + zero pads),
// scLog/red[4..7] available, tau in scope. Writes out[s], out[NS+s].
#define TREE_PHASE                                                                       \
  {                                                                                      \
    const int m = t >> 3, r = t & 7;                                                     \
    const float* A = LW + OW2 + (2 * m) * 32 + 12;                                       \
    const float* B = LW + OW2 + (2 * m + 1) * 32 + 12;                                   \
    float a0 = 0.f, a1 = 0.f, a2 = 0.f, a3 = 0.f;                                        \
    const int j0 = 4 * r;                                                                \
    if (r < 5) {                                                                         \
      _Pragma("unroll")                                                                  \
      for (int i0 = 0; i0 <= 8; i0 += 4) {                                               \
        const float4 a4 = ld4(A + i0);                                                   \
        const float4 bl = ld4(B + j0 - i0 - 4);                                          \
        const float4 bh = ld4(B + j0 - i0);                                              \
        CONV4(a4, bl, bh);                                                               \
      }                                                                                  \
      if (r == 4) { a1 = 0.f; a2 = 0.f; a3 = 0.f; }                                      \
    }                                                                                    \
    float mx = fmaxf(fmaxf(a0, a1), fmaxf(a2, a3));                                      \
    mx = fmaxf(mx, __shfl_xor(mx, 1));                                                   \
    mx = fmaxf(mx, __shfl_xor(mx, 2));                                                   \
    mx = fmaxf(mx, __shfl_xor(mx, 4));                                                   \
    const float inv = 1.f / mx;                                                          \
    if (r < 5) st4(LW + OW3 + m * 44 + 20 + j0, a0 * inv, a1 * inv, a2 * inv, a3 * inv); \
    if (r == 0) scLog[m] = __logf(mx);                                                   \
  }                                                                                      \
  {                                                                                      \
    const int m = t >> 4, r = t & 15;                                                    \
    const float* A = LW + OW3 + (2 * m) * 44 + 20;                                       \
    const float* B = LW + OW3 + (2 * m + 1) * 44 + 20;                                   \
    float a0 = 0.f, a1 = 0.f, a2 = 0.f, a3 = 0.f;                                        \
    const int j0 = 4 * r;                                                                \
    if (r < 6) {                                                                         \
      _Pragma("unroll")                                                                  \
      for (int i0 = 0; i0 <= 16; i0 += 4) {                                              \
        const float4 a4 = ld4(A + i0);                                                   \
        const float4 bl = ld4(B + j0 - i0 - 4);                                          \
        const float4 bh = ld4(B + j0 - i0);                                              \
        CONV4(a4, bl, bh);                                                               \
      }                                                                                  \
      if (r == 5) { a1 = 0.f; a2 = 0.f; a3 = 0.f; }                                      \
    }                                                                                    \
    float mx = fmaxf(fmaxf(a0, a1), fmaxf(a2, a3));                                      \
    mx = fmaxf(mx, __shfl_xor(mx, 1));                                                   \
    mx = fmaxf(mx, __shfl_xor(mx, 2));                                                   \
    mx = fmaxf(mx, __shfl_xor(mx, 4));                                                   \
    mx = fmaxf(mx, __shfl_xor(mx, 8));                                                   \
    const float inv = 1.f / mx;                                                          \
    if (r < 6) st4(LW + OW4 + m * 60 + 24 + j0, a0 * inv, a1 * inv, a2 * inv, a3 * inv); \
    if (r == 0) scLog[32 + m] = __logf(mx);                                              \
  }                                                                                      \
  {                                                                                      \
    const int m = t >> 5, r = t & 31;                                                    \
    const float* A = LW + OW4 + (2 * m) * 60 + 24;                                       \
    const float* B = LW + OW4 + (2 * m + 1) * 60 + 24;                                   \
    float a0 = 0.f, a1 = 0.f, a2 = 0.f, a3 = 0.f;                                        \
    const int j0 = 4 * r;                                                                \
    if (r < 9) {                                                                         \
      _Pragma("unroll")                                                                  \
      for (int i0 = 0; i0 <= 20; i0 += 4) {                                              \
        const float4 a4 = ld4(A + i0);                                                   \
        const float4 bl = ld4(B + j0 - i0 - 4);                                          \
        const float4 bh = ld4(B + j0 - i0);                                              \
        CONV4(a4, bl, bh);                                                               \
      }                                                                                  \
      if (r == 8) { a1 = 0.f; a2 = 0.f; a3 = 0.f; }                                      \
    }                                                                                    \
    float mx = fmaxf(fmaxf(a0, a1), fmaxf(a2, a3));                                      \
    mx = fmaxf(mx, __shfl_xor(mx, 1));                                                   \
    mx = fmaxf(mx, __shfl_xor(mx, 2));                                                   \
    mx = fmaxf(mx, __shfl_xor(mx, 4));                                                   \
    mx = fmaxf(mx, __shfl_xor(mx, 8));                                                   \
    mx = fmaxf(mx, __shfl_xor(mx, 16));                                                  \
    const float inv = 1.f / mx;                                                          \
    if (r < 9) st4(LW + OW5 + m * 84 + 36 + j0, a0 * inv, a1 * inv, a2 * inv, a3 * inv); \
    if (r == 0) scLog[48 + m] = __logf(mx);                                              \
  }                                                                                      \
  {                                                                                      \
    const int r = t & 63;                                                                \
    const float* A = LW + OW5 + (2 * wv) * 84 + 36;                                      \
    const float* B = LW + OW5 + (2 * wv + 1) * 84 + 36;                                  \
    float a0 = 0.f, a1 = 0.f, a2 = 0.f, a3 = 0.f;                                        \
    const int j0 = 4 * r;                                                                \
    if (r < 12) {                                                                        \
      _Pragma("unroll")                                                                  \
      for (int i0 = 0; i0 <= 32; i0 += 4) {                                              \
        const float4 a4 = ld4(A + i0);                                                   \
        const float4 bl = ld4(B + j0 - i0 - 4);                                          \
        const float4 bh = ld4(B + j0 - i0);                                              \
        CONV4(a4, bl, bh);                                                               \
      }                                                                                  \
      if (r == 11) { a1 = 0.f; a2 = 0.f; a3 = 0.f; }                                     \
    }                                                                                    \
    float mx = fmaxf(fmaxf(a0, a1), fmaxf(a2, a3));                                      \
    _Pragma("unroll")                                                                    \
    for (int msk = 1; msk < 64; msk <<= 1) mx = fmaxf(mx, __shfl_xor(mx, msk));          \
    const float inv = 1.f / mx;                                                          \
    if (r < 12) st4(LW + OW6 + wv * 116 + 48 + j0, a0 * inv, a1 * inv, a2 * inv, a3 * inv); \
    if (r == 0) scLog[56 + wv] = __logf(mx);                                             \
  }                                                                                      \
  __syncthreads();                                                                       \
  if (t < 64) {                                                                          \
    const int m = (t >> 5) & 1, r = t & 31;                                              \
    const float* A = LW + OW6 + (2 * m) * 116 + 48;                                      \
    const float* B = LW + OW6 + (2 * m + 1) * 116 + 48;                                  \
    float a0 = 0.f, a1 = 0.f, a2 = 0.f, a3 = 0.f;                                        \
    const int j0 = 4 * r;                                                                \
    if (r < 17) {                                                                        \
      _Pragma("unroll")                                                                  \
      for (int i0 = 0; i0 <= 44; i0 += 4) {                                              \
        const float4 a4 = ld4(A + i0);                                                   \
        const float4 bl = ld4(B + j0 - i0 - 4);                                          \
        const float4 bh = ld4(B + j0 - i0);                                              \
        CONV4(a4, bl, bh);                                                               \
      }                                                                                  \
      if (r == 16) { a1 = 0.f; a2 = 0.f; a3 = 0.f; }                                     \
    }                                                                                    \
    float mx = fmaxf(fmaxf(a0, a1), fmaxf(a2, a3));                                      \
    mx = fmaxf(mx, __shfl_xor(mx, 1));                                                   \
    mx = fmaxf(mx, __shfl_xor(mx, 2));                                                   \
    mx = fmaxf(mx, __shfl_xor(mx, 4));                                                   \
    mx = fmaxf(mx, __shfl_xor(mx, 8));                                                   \
    mx = fmaxf(mx, __shfl_xor(mx, 16));                                                  \
    const float inv = 1.f / mx;                                                          \
    if (r < 17) st4(LW + OW7 + m * 68 + j0, a0 * inv, a1 * inv, a2 * inv, a3 * inv);     \
    if (r == 0) scLog[60 + m] = __logf(mx);                                              \
  }                                                                                      \
  if (t < 64) {                                                                          \
    const float* A = LW + OW7;                                                           \
    const float* B = LW + OW7 + 68;                                                      \
    const float a = A[t];                                                                \
    float v63 = a * B[63 - t];                                                           \
    float v64 = a * B[64 - t];                                                           \
    float ee = (t < 62) ? scLog[t] : 0.f;                                                \
    _Pragma("unroll")                                                                    \
    for (int msk = 1; msk < 64; msk <<= 1) {                                             \
      v63 += __shfl_xor(v63, msk);                                                       \
      v64 += __shfl_xor(v64, msk);                                                       \
      ee  += __shfl_xor(ee, msk);                                                        \
    }                                                                                    \
    if (t == 0) {                                                                        \
      v64 = fmaf(A[64], B[0], v64);                                                      \
      const float Ssum = red[4] + red[5] + red[6] + red[7] + ee;                         \
      out[s]      = __logf(v63) + Ssum + 63.f * tau;                                     \
      out[NS + s] = __logf(v64) + Ssum + 64.f * tau;                                     \
    }                                                                                    \
  }

// ---------------- kernel 1: leaf phase, HBM-bound ----------------
__global__ __launch_bounds__(256, 6)
void leaf_kernel(const float* __restrict__ x, float* __restrict__ ws) {
  __shared__ float red[4];
  const int t  = threadIdx.x;
  const int wv = t >> 6;
  const int s  = blockIdx.x;

  LEAF_PHASE

  float* base = ws + (size_t)s * WSS;
  if ((t & 63) == 0) base[768 + wv] = Sr;
  if (t == 0) base[772] = tau;
  if ((t & 3) == 0) {
    float* qp = base + (t >> 2) * 12;
    st4(qp,     g0, g1, g2, g3);
    st4(qp + 4, g4, g5, g6, g7);
    st4(qp + 8, g8, g9, g10, g11);
  }
}

// ---------------- kernel 2: merge tree ----------------
__global__ __launch_bounds__(256, 4)
void tree_kernel(const float* __restrict__ ws, float* __restrict__ out) {
  __shared__ float LW[LDSF];
  __shared__ float scLog[64];
  __shared__ float red[8];
  const int t  = threadIdx.x;
  const int wv = t >> 6;
  const int s  = blockIdx.x;

  // zero arena (pads stay zero)
  {
    float4* z4 = (float4*)LW;
#pragma unroll
    for (int u = 0; u < 6; ++u) {
      const int idx = t + u * 256;
      if (idx < LDSF / 4) z4[idx] = make_float4(0.f, 0.f, 0.f, 0.f);
    }
  }
  __syncthreads();

  const float* base = ws + (size_t)s * WSS;
  const float tau = base[772];
  if (t < 192) {                                  // stage 64 quads x 12 coeffs
    const float4 v = ld4(base + t * 4);
    const int q = t / 3, p = t - q * 3;
    st4(LW + OW2 + q * 32 + 12 + p * 4, v.x, v.y, v.z, v.w);
  }
  if (t >= 192 && t < 196) red[4 + (t - 192)] = base[768 + (t - 192)];
  __syncthreads();

  TREE_PHASE
}

// ---------------- fallback: round-12 monolith (ws too small) ----------------
__global__ __launch_bounds__(256, 4)
void logesp_mono(const float* __restrict__ x, float* __restrict__ out) {
  __shared__ float LW[LDSF];
  __shared__ float scLog[64];
  __shared__ float red[8];
  const int t  = threadIdx.x;
  const int wv = t >> 6;
  const int s  = blockIdx.x;

  {
    float4* z4 = (float4*)LW;
#pragma unroll
    for (int u = 0; u < 6; ++u) {
      const int idx = t + u * 256;
      if (idx < LDSF / 4) z4[idx] = make_float4(0.f, 0.f, 0.f, 0.f);
    }
  }

  LEAF_PHASE

  if ((t & 63) == 0) red[4 + wv] = Sr;
  if ((t & 3) == 0) {
    float* row = LW + OW2 + (t >> 2) * 32;
    st4(row + 12, g0, g1, g2, g3);
    st4(row + 16, g4, g5, g6, g7);
    st4(row + 20, g8, g9, g10, g11);
  }

  TREE_PHASE
}

extern "C" void kernel_launch(void* const* d_in, const int* in_sizes, int n_in,
                              void* d_out, int out_size, void* d_ws, size_t ws_size,
                              hipStream_t stream) {
  const float* x = (const float*)d_in[0];
  float* out = (float*)d_out;
  (void)in_sizes; (void)n_in; (void)out_size;
  if (ws_size >= (size_t)NS * WSS * sizeof(float)) {
    float* w = (float*)d_ws;
    leaf_kernel<<<NS, 256, 0, stream>>>(x, w);
    tree_kernel<<<NS, 256, 0, stream>>>(w, out);
  } else {
    logesp_mono<<<NS, 256, 0, stream>>>(x, out);
  }
}

// Round 14
// 37.629 us; speedup vs baseline: 1.7814x; 1.7814x over previous
//
#include <hip/hip_runtime.h>

// log sigma_{63,64} of exp(x) along classes: x (2048,10000) f32 -> out (2,2048) f32.
// TWO-KERNEL SPLIT. Kernel 1 = leaf phase (streaming, HBM-bound): loads, exp,
// tilt tau, per-leaf normalize, RL1/RL2 shuffle merges -> per-sample 64 quad
// polys (12 coeffs) + wave-S + tau into ws (6.4 MB). Kernel 2 = stage ws into
// W2 LDS layout + round-12's verified L3..L8 tree. Fallback monolith if ws small.
// Round 14 change (single variable): leaf_kernel __launch_bounds__(256,6) ->
// (256,4). The (256,6) bound made LLVM target ~12 waves/EU -> VGPR=40 + 98 MB
// scratch spill (WRITE_SIZE counter). Cap-128 never spilled (rounds 5/9/12).

#define NS 2048
#define NC 10000
#define KSEL 64

// per-sample ws layout (floats): [0..767] 64 quads x 12 coeffs; [768..771] wave S; [772] tau
#define WSS 784

// LDS arena float offsets/strides: row = [lowpad z | coeffs | top z]
#define OW2 0      // 64 rows x 32  : [12z | 12 (deg<=11) | 8z]
#define OW3 2048   // 32 rows x 44  : [20z | 17 (deg<=16) | 7z]
#define OW4 3456   // 16 rows x 60  : [24z | 21 (deg<=20) | 15z]
#define OW5 4416   //  8 rows x 84  : [36z | 33 (deg<=32) | 15z]
#define OW6 5088   //  4 rows x 116 : [48z | 45 (deg<=44) | 23z]
#define OW7 5552   //  2 rows x 68  : [65 (deg<=64) | 3z]
#define LDSF 5688  // total floats (= 1422 float4)

__device__ __forceinline__ float4 ld4(const float* p) { return *(const float4*)p; }
__device__ __forceinline__ void st4(float* p, float a, float b, float c, float d) {
  *(float4*)p = make_float4(a, b, c, d);
}

// 16-FMA sliding block: acc_q += a4[k] * b_{j0+q-(i0+k)} with bh=B[j0-i0..+3], bl=B[j0-i0-4..-1]
#define CONV4(a4, bl, bh)                                                               \
  a0 = fmaf(a4.x, bh.x, a0); a1 = fmaf(a4.x, bh.y, a1); a2 = fmaf(a4.x, bh.z, a2); a3 = fmaf(a4.x, bh.w, a3); \
  a0 = fmaf(a4.y, bl.w, a0); a1 = fmaf(a4.y, bh.x, a1); a2 = fmaf(a4.y, bh.y, a2); a3 = fmaf(a4.y, bh.z, a3); \
  a0 = fmaf(a4.z, bl.z, a0); a1 = fmaf(a4.z, bl.w, a1); a2 = fmaf(a4.z, bh.x, a2); a3 = fmaf(a4.z, bh.y, a3); \
  a0 = fmaf(a4.w, bl.y, a0); a1 = fmaf(a4.w, bl.z, a1); a2 = fmaf(a4.w, bl.w, a2); a3 = fmaf(a4.w, bh.x, a3)

// Shared leaf phase: loads, exp, tilt, normalize, RL1/RL2. Emits g0..g11 (quad poly),
// per-wave S in Sr (lane0 meaningful), tau.
#define LEAF_PHASE                                                                       \
  const float4* xv = (const float4*)(x + (size_t)s * NC);                                \
  float4 buf[10];                                                                        \
  _Pragma("unroll")                                                                      \
  for (int it = 0; it < 9; ++it) buf[it] = xv[t + it * 256];                             \
  buf[9] = make_float4(-1e30f, -1e30f, -1e30f, -1e30f);                                  \
  if (t < 196) buf[9] = xv[2304 + t];                                                    \
  float c0 = 1.f, c1 = 0.f, c2 = 0.f, c3 = 0.f, c4 = 0.f, c5 = 0.f, c6 = 0.f;            \
  float sw = 0.f;                                                                        \
  _Pragma("unroll")                                                                      \
  for (int it = 0; it < 10; ++it) {                                                      \
    const float4 v = buf[it];                                                            \
    _Pragma("unroll")                                                                    \
    for (int q = 0; q < 4; ++q) {                                                        \
      const float xval = q == 0 ? v.x : q == 1 ? v.y : q == 2 ? v.z : v.w;               \
      const float w = __expf(xval);                                                      \
      sw += w;                                                                           \
      c6 = fmaf(w, c5, c6); c5 = fmaf(w, c4, c5); c4 = fmaf(w, c3, c4);                  \
      c3 = fmaf(w, c2, c3); c2 = fmaf(w, c1, c2); c1 = fmaf(w, c0, c1);                  \
    }                                                                                    \
  }                                                                                      \
  _Pragma("unroll")                                                                      \
  for (int m = 1; m < 64; m <<= 1) sw += __shfl_xor(sw, m);                              \
  if ((t & 63) == 0) red[wv] = sw;                                                       \
  __syncthreads();                                                                       \
  const float wsum = red[0] + red[1] + red[2] + red[3];                                  \
  const float tau = __logf(wsum * ((float)(NC - KSEL) / ((float)KSEL * (float)NC)));     \
  {                                                                                      \
    const float f1 = __expf(-tau);                                                       \
    const float f2 = f1 * f1, f3 = f2 * f1, f4v = f2 * f2, f5 = f4v * f1, f6 = f4v * f2; \
    c1 *= f1; c2 *= f2; c3 *= f3; c4 *= f4v; c5 *= f5; c6 *= f6;                         \
  }                                                                                      \
  float Sr;                                                                              \
  {                                                                                      \
    const float mx = fmaxf(fmaxf(fmaxf(c0, c1), fmaxf(c2, c3)), fmaxf(fmaxf(c4, c5), c6)); \
    const float invm = 1.f / mx;                                                         \
    c0 *= invm; c1 *= invm; c2 *= invm; c3 *= invm; c4 *= invm; c5 *= invm; c6 *= invm;  \
    Sr = __logf(mx);                                                                     \
    _Pragma("unroll")                                                                    \
    for (int m = 1; m < 64; m <<= 1) Sr += __shfl_xor(Sr, m);                            \
  }                                                                                      \
  const float q0 = __shfl_xor(c0, 1), q1 = __shfl_xor(c1, 1), q2 = __shfl_xor(c2, 1),    \
              q3 = __shfl_xor(c3, 1), q4 = __shfl_xor(c4, 1), q5 = __shfl_xor(c5, 1),    \
              q6 = __shfl_xor(c6, 1);                                                    \
  const float e0 = c0 * q0;                                                              \
  const float e1 = fmaf(c1, q0, c0 * q1);                                                \
  const float e2 = fmaf(c2, q0, fmaf(c1, q1, c0 * q2));                                  \
  const float e3 = fmaf(c3, q0, fmaf(c2, q1, fmaf(c1, q2, c0 * q3)));                    \
  const float e4 = fmaf(c4, q0, fmaf(c3, q1, fmaf(c2, q2, fmaf(c1, q3, c0 * q4))));      \
  const float e5 = fmaf(c5, q0, fmaf(c4, q1, fmaf(c3, q2, fmaf(c2, q3, fmaf(c1, q4, c0 * q5))))); \
  const float e6 = fmaf(c6, q0, fmaf(c5, q1, fmaf(c4, q2, fmaf(c3, q3, fmaf(c2, q4, fmaf(c1, q5, c0 * q6)))))); \
  const float e7 = fmaf(c6, q1, fmaf(c5, q2, fmaf(c4, q3, fmaf(c3, q4, fmaf(c2, q5, c1 * q6))))); \
  const float f0 = __shfl_xor(e0, 2), f1 = __shfl_xor(e1, 2), f2 = __shfl_xor(e2, 2),    \
              f3 = __shfl_xor(e3, 2), f4 = __shfl_xor(e4, 2), f5 = __shfl_xor(e5, 2),    \
              f6 = __shfl_xor(e6, 2), f7 = __shfl_xor(e7, 2);                            \
  const float g0 = e0 * f0;                                                              \
  const float g1 = fmaf(e1, f0, e0 * f1);                                                \
  const float g2 = fmaf(e2, f0, fmaf(e1, f1, e0 * f2));                                  \
  const float g3 = fmaf(e3, f0, fmaf(e2, f1, fmaf(e1, f2, e0 * f3)));                    \
  const float g4 = fmaf(e4, f0, fmaf(e3, f1, fmaf(e2, f2, fmaf(e1, f3, e0 * f4))));      \
  const float g5 = fmaf(e5, f0, fmaf(e4, f1, fmaf(e3, f2, fmaf(e2, f3, fmaf(e1, f4, e0 * f5))))); \
  const float g6 = fmaf(e6, f0, fmaf(e5, f1, fmaf(e4, f2, fmaf(e3, f3, fmaf(e2, f4, fmaf(e1, f5, e0 * f6)))))); \
  const float g7 = fmaf(e7, f0, fmaf(e6, f1, fmaf(e5, f2, fmaf(e4, f3, fmaf(e3, f4, fmaf(e2, f5, fmaf(e1, f6, e0 * f7))))))); \
  const float g8 = fmaf(e7, f1, fmaf(e6, f2, fmaf(e5, f3, fmaf(e4, f4, fmaf(e3, f5, fmaf(e2, f6, e1 * f7)))))); \
  const float g9 = fmaf(e7, f2, fmaf(e6, f3, fmaf(e5, f4, fmaf(e4, f5, fmaf(e3, f6, e2 * f7))))); \
  const float g10 = fmaf(e7, f3, fmaf(e6, f4, fmaf(e5, f5, fmaf(e4, f6, e3 * f7))));     \
  const float g11 = fmaf(e7, f4, fmaf(e6, f5, fmaf(e5, f6, e4 * f7)));

// The verified L3..L8 tree (round 12). Requires: LW staged (W2 payload + zero pads),
// scLog/red[4..7] available, tau in scope. Writes out[s], out[NS+s].
#define TREE_PHASE                                                                       \
  {                                                                                      \
    const int m = t >> 3, r = t & 7;                                                     \
    const float* A = LW + OW2 + (2 * m) * 32 + 12;                                       \
    const float* B = LW + OW2 + (2 * m + 1) * 32 + 12;                                   \
    float a0 = 0.f, a1 = 0.f, a2 = 0.f, a3 = 0.f;                                        \
    const int j0 = 4 * r;                                                                \
    if (r < 5) {                                                                         \
      _Pragma("unroll")                                                                  \
      for (int i0 = 0; i0 <= 8; i0 += 4) {                                               \
        const float4 a4 = ld4(A + i0);                                                   \
        const float4 bl = ld4(B + j0 - i0 - 4);                                          \
        const float4 bh = ld4(B + j0 - i0);                                              \
        CONV4(a4, bl, bh);                                                               \
      }                                                                                  \
      if (r == 4) { a1 = 0.f; a2 = 0.f; a3 = 0.f; }                                      \
    }                                                                                    \
    float mx = fmaxf(fmaxf(a0, a1), fmaxf(a2, a3));                                      \
    mx = fmaxf(mx, __shfl_xor(mx, 1));                                                   \
    mx = fmaxf(mx, __shfl_xor(mx, 2));                                                   \
    mx = fmaxf(mx, __shfl_xor(mx, 4));                                                   \
    const float inv = 1.f / mx;                                                          \
    if (r < 5) st4(LW + OW3 + m * 44 + 20 + j0, a0 * inv, a1 * inv, a2 * inv, a3 * inv); \
    if (r == 0) scLog[m] = __logf(mx);                                                   \
  }                                                                                      \
  {                                                                                      \
    const int m = t >> 4, r = t & 15;                                                    \
    const float* A = LW + OW3 + (2 * m) * 44 + 20;                                       \
    const float* B = LW + OW3 + (2 * m + 1) * 44 + 20;                                   \
    float a0 = 0.f, a1 = 0.f, a2 = 0.f, a3 = 0.f;                                        \
    const int j0 = 4 * r;                                                                \
    if (r < 6) {                                                                         \
      _Pragma("unroll")                                                                  \
      for (int i0 = 0; i0 <= 16; i0 += 4) {                                              \
        const float4 a4 = ld4(A + i0);                                                   \
        const float4 bl = ld4(B + j0 - i0 - 4);                                          \
        const float4 bh = ld4(B + j0 - i0);                                              \
        CONV4(a4, bl, bh);                                                               \
      }                                                                                  \
      if (r == 5) { a1 = 0.f; a2 = 0.f; a3 = 0.f; }                                      \
    }                                                                                    \
    float mx = fmaxf(fmaxf(a0, a1), fmaxf(a2, a3));                                      \
    mx = fmaxf(mx, __shfl_xor(mx, 1));                                                   \
    mx = fmaxf(mx, __shfl_xor(mx, 2));                                                   \
    mx = fmaxf(mx, __shfl_xor(mx, 4));                                                   \
    mx = fmaxf(mx, __shfl_xor(mx, 8));                                                   \
    const float inv = 1.f / mx;                                                          \
    if (r < 6) st4(LW + OW4 + m * 60 + 24 + j0, a0 * inv, a1 * inv, a2 * inv, a3 * inv); \
    if (r == 0) scLog[32 + m] = __logf(mx);                                              \
  }                                                                                      \
  {                                                                                      \
    const int m = t >> 5, r = t & 31;                                                    \
    const float* A = LW + OW4 + (2 * m) * 60 + 24;                                       \
    const float* B = LW + OW4 + (2 * m + 1) * 60 + 24;                                   \
    float a0 = 0.f, a1 = 0.f, a2 = 0.f, a3 = 0.f;                                        \
    const int j0 = 4 * r;                                                                \
    if (r < 9) {                                                                         \
      _Pragma("unroll")                                                                  \
      for (int i0 = 0; i0 <= 20; i0 += 4) {                                              \
        const float4 a4 = ld4(A + i0);                                                   \
        const float4 bl = ld4(B + j0 - i0 - 4);                                          \
        const float4 bh = ld4(B + j0 - i0);                                              \
        CONV4(a4, bl, bh);                                                               \
      }                                                                                  \
      if (r == 8) { a1 = 0.f; a2 = 0.f; a3 = 0.f; }                                      \
    }                                                                                    \
    float mx = fmaxf(fmaxf(a0, a1), fmaxf(a2, a3));                                      \
    mx = fmaxf(mx, __shfl_xor(mx, 1));                                                   \
    mx = fmaxf(mx, __shfl_xor(mx, 2));                                                   \
    mx = fmaxf(mx, __shfl_xor(mx, 4));                                                   \
    mx = fmaxf(mx, __shfl_xor(mx, 8));                                                   \
    mx = fmaxf(mx, __shfl_xor(mx, 16));                                                  \
    const float inv = 1.f / mx;                                                          \
    if (r < 9) st4(LW + OW5 + m * 84 + 36 + j0, a0 * inv, a1 * inv, a2 * inv, a3 * inv); \
    if (r == 0) scLog[48 + m] = __logf(mx);                                              \
  }                                                                                      \
  {                                                                                      \
    const int r = t & 63;                                                                \
    const float* A = LW + OW5 + (2 * wv) * 84 + 36;                                      \
    const float* B = LW + OW5 + (2 * wv + 1) * 84 + 36;                                  \
    float a0 = 0.f, a1 = 0.f, a2 = 0.f, a3 = 0.f;                                        \
    const int j0 = 4 * r;                                                                \
    if (r < 12) {                                                                        \
      _Pragma("unroll")                                                                  \
      for (int i0 = 0; i0 <= 32; i0 += 4) {                                              \
        const float4 a4 = ld4(A + i0);                                                   \
        const float4 bl = ld4(B + j0 - i0 - 4);                                          \
        const float4 bh = ld4(B + j0 - i0);                                              \
        CONV4(a4, bl, bh);                                                               \
      }                                                                                  \
      if (r == 11) { a1 = 0.f; a2 = 0.f; a3 = 0.f; }                                     \
    }                                                                                    \
    float mx = fmaxf(fmaxf(a0, a1), fmaxf(a2, a3));                                      \
    _Pragma("unroll")                                                                    \
    for (int msk = 1; msk < 64; msk <<= 1) mx = fmaxf(mx, __shfl_xor(mx, msk));          \
    const float inv = 1.f / mx;                                                          \
    if (r < 12) st4(LW + OW6 + wv * 116 + 48 + j0, a0 * inv, a1 * inv, a2 * inv, a3 * inv); \
    if (r == 0) scLog[56 + wv] = __logf(mx);                                             \
  }                                                                                      \
  __syncthreads();                                                                       \
  if (t < 64) {                                                                          \
    const int m = (t >> 5) & 1, r = t & 31;                                              \
    const float* A = LW + OW6 + (2 * m) * 116 + 48;                                      \
    const float* B = LW + OW6 + (2 * m + 1) * 116 + 48;                                  \
    float a0 = 0.f, a1 = 0.f, a2 = 0.f, a3 = 0.f;                                        \
    const int j0 = 4 * r;                                                                \
    if (r < 17) {                                                                        \
      _Pragma("unroll")                                                                  \
      for (int i0 = 0; i0 <= 44; i0 += 4) {                                              \
        const float4 a4 = ld4(A + i0);                                                   \
        const float4 bl = ld4(B + j0 - i0 - 4);                                          \
        const float4 bh = ld4(B + j0 - i0);                                              \
        CONV4(a4, bl, bh);                                                               \
      }                                                                                  \
      if (r == 16) { a1 = 0.f; a2 = 0.f; a3 = 0.f; }                                     \
    }                                                                                    \
    float mx = fmaxf(fmaxf(a0, a1), fmaxf(a2, a3));                                      \
    mx = fmaxf(mx, __shfl_xor(mx, 1));                                                   \
    mx = fmaxf(mx, __shfl_xor(mx, 2));                                                   \
    mx = fmaxf(mx, __shfl_xor(mx, 4));                                                   \
    mx = fmaxf(mx, __shfl_xor(mx, 8));                                                   \
    mx = fmaxf(mx, __shfl_xor(mx, 16));                                                  \
    const float inv = 1.f / mx;                                                          \
    if (r < 17) st4(LW + OW7 + m * 68 + j0, a0 * inv, a1 * inv, a2 * inv, a3 * inv);     \
    if (r == 0) scLog[60 + m] = __logf(mx);                                              \
  }                                                                                      \
  if (t < 64) {                                                                          \
    const float* A = LW + OW7;                                                           \
    const float* B = LW + OW7 + 68;                                                      \
    const float a = A[t];                                                                \
    float v63 = a * B[63 - t];                                                           \
    float v64 = a * B[64 - t];                                                           \
    float ee = (t < 62) ? scLog[t] : 0.f;                                                \
    _Pragma("unroll")                                                                    \
    for (int msk = 1; msk < 64; msk <<= 1) {                                             \
      v63 += __shfl_xor(v63, msk);                                                       \
      v64 += __shfl_xor(v64, msk);                                                       \
      ee  += __shfl_xor(ee, msk);                                                        \
    }                                                                                    \
    if (t == 0) {                                                                        \
      v64 = fmaf(A[64], B[0], v64);                                                      \
      const float Ssum = red[4] + red[5] + red[6] + red[7] + ee;                         \
      out[s]      = __logf(v63) + Ssum + 63.f * tau;                                     \
      out[NS + s] = __logf(v64) + Ssum + 64.f * tau;                                     \
    }                                                                                    \
  }

// ---------------- kernel 1: leaf phase, HBM-bound ----------------
__global__ __launch_bounds__(256, 4)
void leaf_kernel(const float* __restrict__ x, float* __restrict__ ws) {
  __shared__ float red[4];
  const int t  = threadIdx.x;
  const int wv = t >> 6;
  const int s  = blockIdx.x;

  LEAF_PHASE

  float* base = ws + (size_t)s * WSS;
  if ((t & 63) == 0) base[768 + wv] = Sr;
  if (t == 0) base[772] = tau;
  if ((t & 3) == 0) {
    float* qp = base + (t >> 2) * 12;
    st4(qp,     g0, g1, g2, g3);
    st4(qp + 4, g4, g5, g6, g7);
    st4(qp + 8, g8, g9, g10, g11);
  }
}

// ---------------- kernel 2: merge tree ----------------
__global__ __launch_bounds__(256, 4)
void tree_kernel(const float* __restrict__ ws, float* __restrict__ out) {
  __shared__ float LW[LDSF];
  __shared__ float scLog[64];
  __shared__ float red[8];
  const int t  = threadIdx.x;
  const int wv = t >> 6;
  const int s  = blockIdx.x;

  // zero arena (pads stay zero)
  {
    float4* z4 = (float4*)LW;
#pragma unroll
    for (int u = 0; u < 6; ++u) {
      const int idx = t + u * 256;
      if (idx < LDSF / 4) z4[idx] = make_float4(0.f, 0.f, 0.f, 0.f);
    }
  }
  __syncthreads();

  const float* base = ws + (size_t)s * WSS;
  const float tau = base[772];
  if (t < 192) {                                  // stage 64 quads x 12 coeffs
    const float4 v = ld4(base + t * 4);
    const int q = t / 3, p = t - q * 3;
    st4(LW + OW2 + q * 32 + 12 + p * 4, v.x, v.y, v.z, v.w);
  }
  if (t >= 192 && t < 196) red[4 + (t - 192)] = base[768 + (t - 192)];
  __syncthreads();

  TREE_PHASE
}

// ---------------- fallback: round-12 monolith (ws too small) ----------------
__global__ __launch_bounds__(256, 4)
void logesp_mono(const float* __restrict__ x, float* __restrict__ out) {
  __shared__ float LW[LDSF];
  __shared__ float scLog[64];
  __shared__ float red[8];
  const int t  = threadIdx.x;
  const int wv = t >> 6;
  const int s  = blockIdx.x;

  {
    float4* z4 = (float4*)LW;
#pragma unroll
    for (int u = 0; u < 6; ++u) {
      const int idx = t + u * 256;
      if (idx < LDSF / 4) z4[idx] = make_float4(0.f, 0.f, 0.f, 0.f);
    }
  }

  LEAF_PHASE

  if ((t & 63) == 0) red[4 + wv] = Sr;
  if ((t & 3) == 0) {
    float* row = LW + OW2 + (t >> 2) * 32;
    st4(row + 12, g0, g1, g2, g3);
    st4(row + 16, g4, g5, g6, g7);
    st4(row + 20, g8, g9, g10, g11);
  }

  TREE_PHASE
}

extern "C" void kernel_launch(void* const* d_in, const int* in_sizes, int n_in,
                              void* d_out, int out_size, void* d_ws, size_t ws_size,
                              hipStream_t stream) {
  const float* x = (const float*)d_in[0];
  float* out = (float*)d_out;
  (void)in_sizes; (void)n_in; (void)out_size;
  if (ws_size >= (size_t)NS * WSS * sizeof(float)) {
    float* w = (float*)d_ws;
    leaf_kernel<<<NS, 256, 0, stream>>>(x, w);
    tree_kernel<<<NS, 256, 0, stream>>>(w, out);
  } else {
    logesp_mono<<<NS, 256, 0, stream>>>(x, out);
  }
}

// Round 15
// 29.467 us; speedup vs baseline: 2.2748x; 1.2770x over previous
//
#include <hip/hip_runtime.h>

// log sigma_{63,64} of exp(x) along classes: x (2048,10000) f32 -> out (2,2048) f32.
// 256 threads/sample. Global exponential tilt tau; 256 register leaves (deg<=6),
// RL1/RL2 shuffle merges (deg 7, 11) -> L3..L7 static broadcast-convs in LDS
// (keep 16,20,32,44,64) -> L8 final degrees 63,64. Per-merge max-normalization,
// write-once scLog slots. 3 barriers (L3..L6 are wave-internal).
// Round 15 = exact revert to round 9 (best measured: 29.57 us, absmax 0).
// The two-kernel split (rounds 13/14) = monolith + ws round-trip + launch gap;
// tree phase is sub-us, leaf phase is read-concurrency-bound (~2.7 TB/s delivered).

#define NS 2048
#define NC 10000
#define KSEL 64

__global__ __launch_bounds__(256, 4)
void logesp_kernel(const float* __restrict__ x, float* __restrict__ out) {
  __shared__ float W2[64 * 28];   // leaf-quad polys: [11 z | c0..c11 | 5 z]
  __shared__ float W3[32 * 37];   // L3 out:          [16 z | c0..c16 | 4 z]
  __shared__ float W4[16 * 53];   // L4 out:          [20 z | c0..c20 | 12 z]
  __shared__ float W5[8 * 77];    // L5 out:          [32 z | c0..c32 | 12 z]
  __shared__ float W6[4 * 109];   // L6 out:          [44 z | c0..c44 | 20 z]
  __shared__ float W7[2 * 70];    // L7 out:          [c0..c64 | 5 pad]
  __shared__ float scLog[64];     // write-once: L3:0..31 L4:32..47 L5:48..55 L6:56..59 L7:60..61
  __shared__ float red[8];        // [0..3] per-wave sum(w); [4..7] per-wave sum(S)

  const int t  = threadIdx.x;
  const int wv = t >> 6;
  const int s  = blockIdx.x;

  // ---------- phase 1: leaf ESP deg<=6, all 10 loads batched up front ----------
  const float4* xv = (const float4*)(x + (size_t)s * NC);   // 2500 float4
  float4 buf[10];
#pragma unroll
  for (int it = 0; it < 9; ++it) buf[it] = xv[t + it * 256];  // 9*256=2304 < 2500
  buf[9] = make_float4(-1e30f, -1e30f, -1e30f, -1e30f);       // exp -> 0
  if (t < 196) buf[9] = xv[2304 + t];                          // 2304..2499

  float c0 = 1.f, c1 = 0.f, c2 = 0.f, c3 = 0.f, c4 = 0.f, c5 = 0.f, c6 = 0.f;
  float sw = 0.f;
#pragma unroll
  for (int it = 0; it < 10; ++it) {
    const float4 v = buf[it];
#pragma unroll
    for (int q = 0; q < 4; ++q) {
      const float xval = q == 0 ? v.x : q == 1 ? v.y : q == 2 ? v.z : v.w;
      const float w = __expf(xval);
      sw += w;
      c6 = fmaf(w, c5, c6);
      c5 = fmaf(w, c4, c5);
      c4 = fmaf(w, c3, c4);
      c3 = fmaf(w, c2, c3);
      c2 = fmaf(w, c1, c2);
      c1 = fmaf(w, c0, c1);   // c0 stays 1 (untilted leaf is f32-safe)
    }
  }

  // ---------- tilt tau = ln(wbar*(NC-K)/K) ----------
#pragma unroll
  for (int m = 1; m < 64; m <<= 1) sw += __shfl_xor(sw, m);
  if ((t & 63) == 0) red[wv] = sw;
  __syncthreads();                                   // barrier 1
  const float wsum = red[0] + red[1] + red[2] + red[3];
  const float tau = __logf(wsum * ((float)(NC - KSEL) / ((float)KSEL * (float)NC)));

  // tilt + leaf max-normalize (registers)
  {
    const float f1 = __expf(-tau);
    const float f2 = f1 * f1, f3 = f2 * f1, f4v = f2 * f2, f5 = f4v * f1, f6 = f4v * f2;
    c1 *= f1; c2 *= f2; c3 *= f3; c4 *= f4v; c5 *= f5; c6 *= f6;
  }
  {
    const float mx = fmaxf(fmaxf(fmaxf(c0, c1), fmaxf(c2, c3)), fmaxf(fmaxf(c4, c5), c6));
    const float invm = 1.f / mx;
    c0 *= invm; c1 *= invm; c2 *= invm; c3 *= invm; c4 *= invm; c5 *= invm; c6 *= invm;
    float Sr = __logf(mx);
#pragma unroll
    for (int m = 1; m < 64; m <<= 1) Sr += __shfl_xor(Sr, m);
    if ((t & 63) == 0) red[4 + wv] = Sr;             // read by L8 after barrier 2/3
  }

  // ---------- RL1: pair merge via shfl (deg 7) ----------
  const float q0 = __shfl_xor(c0, 1), q1 = __shfl_xor(c1, 1), q2 = __shfl_xor(c2, 1),
              q3 = __shfl_xor(c3, 1), q4 = __shfl_xor(c4, 1), q5 = __shfl_xor(c5, 1),
              q6 = __shfl_xor(c6, 1);
  const float e0 = c0 * q0;
  const float e1 = fmaf(c1, q0, c0 * q1);
  const float e2 = fmaf(c2, q0, fmaf(c1, q1, c0 * q2));
  const float e3 = fmaf(c3, q0, fmaf(c2, q1, fmaf(c1, q2, c0 * q3)));
  const float e4 = fmaf(c4, q0, fmaf(c3, q1, fmaf(c2, q2, fmaf(c1, q3, c0 * q4))));
  const float e5 = fmaf(c5, q0, fmaf(c4, q1, fmaf(c3, q2, fmaf(c2, q3, fmaf(c1, q4, c0 * q5)))));
  const float e6 = fmaf(c6, q0, fmaf(c5, q1, fmaf(c4, q2, fmaf(c3, q3, fmaf(c2, q4, fmaf(c1, q5, c0 * q6))))));
  const float e7 = fmaf(c6, q1, fmaf(c5, q2, fmaf(c4, q3, fmaf(c3, q4, fmaf(c2, q5, c1 * q6)))));

  // ---------- RL2: 4-leaf merge via shfl (deg 11) ----------
  const float f0 = __shfl_xor(e0, 2), f1 = __shfl_xor(e1, 2), f2 = __shfl_xor(e2, 2),
              f3 = __shfl_xor(e3, 2), f4 = __shfl_xor(e4, 2), f5 = __shfl_xor(e5, 2),
              f6 = __shfl_xor(e6, 2), f7 = __shfl_xor(e7, 2);
  const float g0 = e0 * f0;
  const float g1 = fmaf(e1, f0, e0 * f1);
  const float g2 = fmaf(e2, f0, fmaf(e1, f1, e0 * f2));
  const float g3 = fmaf(e3, f0, fmaf(e2, f1, fmaf(e1, f2, e0 * f3)));
  const float g4 = fmaf(e4, f0, fmaf(e3, f1, fmaf(e2, f2, fmaf(e1, f3, e0 * f4))));
  const float g5 = fmaf(e5, f0, fmaf(e4, f1, fmaf(e3, f2, fmaf(e2, f3, fmaf(e1, f4, e0 * f5)))));
  const float g6 = fmaf(e6, f0, fmaf(e5, f1, fmaf(e4, f2, fmaf(e3, f3, fmaf(e2, f4, fmaf(e1, f5, e0 * f6))))));
  const float g7 = fmaf(e7, f0, fmaf(e6, f1, fmaf(e5, f2, fmaf(e4, f3, fmaf(e3, f4, fmaf(e2, f5, fmaf(e1, f6, e0 * f7)))))));
  const float g8 = fmaf(e7, f1, fmaf(e6, f2, fmaf(e5, f3, fmaf(e4, f4, fmaf(e3, f5, fmaf(e2, f6, e1 * f7))))));
  const float g9 = fmaf(e7, f2, fmaf(e6, f3, fmaf(e5, f4, fmaf(e4, f5, fmaf(e3, f6, e2 * f7)))));
  const float g10 = fmaf(e7, f3, fmaf(e6, f4, fmaf(e5, f5, fmaf(e4, f6, e3 * f7))));
  const float g11 = fmaf(e7, f4, fmaf(e6, f5, fmaf(e5, f6, e4 * f7)));

  // store W2 row (quad q = t>>2): [11 z | g0..g11 | 5 z], 7 aligned float4
  if ((t & 3) == 0) {
    float* row = W2 + (t >> 2) * 28;
    *(float4*)(row)      = make_float4(0.f, 0.f, 0.f, 0.f);
    *(float4*)(row + 4)  = make_float4(0.f, 0.f, 0.f, 0.f);
    *(float4*)(row + 8)  = make_float4(0.f, 0.f, 0.f, g0);
    *(float4*)(row + 12) = make_float4(g1, g2, g3, g4);
    *(float4*)(row + 16) = make_float4(g5, g6, g7, g8);
    *(float4*)(row + 20) = make_float4(g9, g10, g11, 0.f);
    *(float4*)(row + 24) = make_float4(0.f, 0.f, 0.f, 0.f);
  }
  // L3 reads only rows written by its own wave -> no barrier (lgkmcnt ordering)

  // ---------- L3: 32 merges x 8 lanes; in deg 11 -> keep 16 ----------
  {
    const int m = t >> 3, r = t & 7;
    const float* A = W2 + (2 * m) * 28;
    const float* B = W2 + (2 * m + 1) * 28;
    float o0 = 0.f, o1 = 0.f, o2 = 0.f;            // degrees r, r+8, 16
#pragma unroll
    for (int i = 0; i <= 11; ++i) {
      const float ai = A[11 + i];
      o0 = fmaf(ai, B[11 + r - i], o0);            // idx 0..18
      o1 = fmaf(ai, B[19 + r - i], o1);            // idx 8..26
      o2 = fmaf(ai, B[27 - i], o2);                // idx 16..27 (same for all lanes)
    }
    float mx = fmaxf(fmaxf(o0, o1), o2);
    mx = fmaxf(mx, __shfl_xor(mx, 1));
    mx = fmaxf(mx, __shfl_xor(mx, 2));
    mx = fmaxf(mx, __shfl_xor(mx, 4));
    const float inv = 1.f / mx;
    float* O = W3 + m * 37;                         // [16 z | c0..c16 | 4 z]
    O[16 + r] = o0 * inv;
    O[24 + r] = o1 * inv;
    if (r == 0) { O[32] = o2 * inv; scLog[m] = __logf(mx); }
    O[r] = 0.f; O[8 + r] = 0.f;
    if (r < 4) O[33 + r] = 0.f;
  }

  // ---------- L4: 16 merges x 16 lanes; in deg 16 -> keep 20 ----------
  {
    const int m = t >> 4, r = t & 15;
    const float* A = W3 + (2 * m) * 37;
    const float* B = W3 + (2 * m + 1) * 37;
    float o0 = 0.f, o1 = 0.f;                       // degrees r, r+16 (r<5)
#pragma unroll
    for (int i = 0; i <= 16; ++i) {
      const float ai = A[16 + i];
      o0 = fmaf(ai, B[16 + r - i], o0);             // idx 0..31
      o1 = fmaf(ai, B[32 + r - i], o1);             // valid only r<5
    }
    if (r >= 5) o1 = 0.f;                           // discard garbage lanes
    float mx = fmaxf(o0, o1);
    mx = fmaxf(mx, __shfl_xor(mx, 1));
    mx = fmaxf(mx, __shfl_xor(mx, 2));
    mx = fmaxf(mx, __shfl_xor(mx, 4));
    mx = fmaxf(mx, __shfl_xor(mx, 8));
    const float inv = 1.f / mx;
    float* O = W4 + m * 53;                         // [20 z | c0..c20 | 12 z]
    O[20 + r] = o0 * inv;
    if (r < 5) O[36 + r] = o1 * inv;
    if (r == 0) scLog[32 + m] = __logf(mx);
    O[r] = 0.f;
    if (r < 4) O[16 + r] = 0.f;
    if (r < 12) O[41 + r] = 0.f;
  }

  // ---------- L5: 8 merges x 32 lanes; in deg 20 -> keep 32 ----------
  {
    const int m = t >> 5, p = t & 31;
    const float* A = W4 + (2 * m) * 53;
    const float* B = W4 + (2 * m + 1) * 53;
    float o0 = 0.f, o1 = 0.f;                       // degrees p, 32
#pragma unroll
    for (int i = 0; i <= 20; ++i) {
      const float ai = A[20 + i];
      o0 = fmaf(ai, B[20 + p - i], o0);             // idx 0..51
      o1 = fmaf(ai, B[52 - i], o1);                 // idx 31..52 (uniform)
    }
    float mx = fmaxf(o0, o1);
    mx = fmaxf(mx, __shfl_xor(mx, 1));
    mx = fmaxf(mx, __shfl_xor(mx, 2));
    mx = fmaxf(mx, __shfl_xor(mx, 4));
    mx = fmaxf(mx, __shfl_xor(mx, 8));
    mx = fmaxf(mx, __shfl_xor(mx, 16));
    const float inv = 1.f / mx;
    float* O = W5 + m * 77;                         // [32 z | c0..c32 | 12 z]
    O[32 + p] = o0 * inv;
    if (p == 0) { O[64] = o1 * inv; scLog[48 + m] = __logf(mx); }
    O[p] = 0.f;
    if (p < 12) O[65 + p] = 0.f;
  }

  // ---------- L6: 4 merges x 64 lanes; in deg 32 -> keep 44 ----------
  {
    const int p = t & 63;
    const float* A = W5 + (2 * wv) * 77;
    const float* B = W5 + (2 * wv + 1) * 77;
    float o0 = 0.f;                                 // degree p (<45)
#pragma unroll
    for (int i = 0; i <= 32; ++i) {
      const float ai = A[32 + i];
      o0 = fmaf(ai, B[32 + p - i], o0);             // idx 0..107 (masked below)
    }
    if (p >= 45) o0 = 0.f;
    float mx = o0;
#pragma unroll
    for (int msk = 1; msk < 64; msk <<= 1) mx = fmaxf(mx, __shfl_xor(mx, msk));
    const float inv = 1.f / mx;
    float* O = W6 + wv * 109;                       // [44 z | c0..c44 | 20 z]
    if (p < 45) O[44 + p] = o0 * inv;
    if (p == 0) scLog[56 + wv] = __logf(mx);
    if (p < 44) O[p] = 0.f;
    if (p < 20) O[89 + p] = 0.f;
  }
  __syncthreads();                                   // barrier 2 (cross-wave W6)

  // ---------- L7: 2 merges, waves 0,1; in deg 44 -> keep 64 ----------
  if (t < 128) {
    const int p = t & 63;
    const float* A = W6 + (2 * wv) * 109;
    const float* B = W6 + (2 * wv + 1) * 109;
    float o0 = 0.f, o1 = 0.f;                        // degrees p, 64
#pragma unroll
    for (int i = 0; i <= 44; ++i) {
      const float ai = A[44 + i];
      o0 = fmaf(ai, B[44 + p - i], o0);              // idx 0..107
      o1 = fmaf(ai, B[108 - i], o1);                 // idx 64..108 (uniform)
    }
    float mx = fmaxf(o0, o1);
#pragma unroll
    for (int msk = 1; msk < 64; msk <<= 1) mx = fmaxf(mx, __shfl_xor(mx, msk));
    const float inv = 1.f / mx;
    float* O = W7 + wv * 70;                         // [c0..c64 | pad]
    O[p] = o0 * inv;
    if (p == 0) { O[64] = o1 * inv; scLog[60 + wv] = __logf(mx); }
  }
  __syncthreads();                                   // barrier 3 (cross-wave W7)

  // ---------- L8: final degrees 63,64 + output ----------
  if (t < 64) {
    const float* A = W7;
    const float* B = W7 + 70;
    const float a = A[t];
    float v63 = a * B[63 - t];
    float v64 = a * B[64 - t];
    float ee = (t < 62) ? scLog[t] : 0.f;
#pragma unroll
    for (int msk = 1; msk < 64; msk <<= 1) {
      v63 += __shfl_xor(v63, msk);
      v64 += __shfl_xor(v64, msk);
      ee  += __shfl_xor(ee, msk);
    }
    if (t == 0) {
      v64 = fmaf(A[64], B[0], v64);
      const float Ssum = red[4] + red[5] + red[6] + red[7] + ee;
      out[s]      = __logf(v63) + Ssum + 63.f * tau;
      out[NS + s] = __logf(v64) + Ssum + 64.f * tau;
    }
  }
}

extern "C" void kernel_launch(void* const* d_in, const int* in_sizes, int n_in,
                              void* d_out, int out_size, void* d_ws, size_t ws_size,
                              hipStream_t stream) {
  const float* x = (const float*)d_in[0];
  float* out = (float*)d_out;
  (void)in_sizes; (void)n_in; (void)d_ws; (void)ws_size; (void)out_size;
  logesp_kernel<<<NS, 256, 0, stream>>>(x, out);
}

// Round 16
// 28.441 us; speedup vs baseline: 2.3569x; 1.0361x over previous
//
#include <hip/hip_runtime.h>

// log sigma_{63,64} of exp(x) along classes: x (2048,10000) f32 -> out (2,2048) f32.
// 256 threads/sample. Global exponential tilt tau; 256 register leaves (deg<=6),
// RL1/RL2 shuffle merges (deg 7, 11) -> L3..L7 static broadcast-convs in LDS
// (keep 16,20,32,44,64) -> L8 final degrees 63,64. Per-merge max-normalization,
// write-once scLog slots. 3 barriers (L3..L6 are wave-internal).
// Round 16 change (single variable vs round 15): the 10 input loads use
// __builtin_nontemporal_load (global_load_dwordx4 nt) — streaming read-once
// hint to bypass L1 allocation / MSHR tracking. Theory: read path is capped at
// ~2.7 TB/s by L1 outstanding-request limits (write-only fills hit 7 TB/s).

#define NS 2048
#define NC 10000
#define KSEL 64

typedef float f32x4 __attribute__((ext_vector_type(4)));

__global__ __launch_bounds__(256, 4)
void logesp_kernel(const float* __restrict__ x, float* __restrict__ out) {
  __shared__ float W2[64 * 28];   // leaf-quad polys: [11 z | c0..c11 | 5 z]
  __shared__ float W3[32 * 37];   // L3 out:          [16 z | c0..c16 | 4 z]
  __shared__ float W4[16 * 53];   // L4 out:          [20 z | c0..c20 | 12 z]
  __shared__ float W5[8 * 77];    // L5 out:          [32 z | c0..c32 | 12 z]
  __shared__ float W6[4 * 109];   // L6 out:          [44 z | c0..c44 | 20 z]
  __shared__ float W7[2 * 70];    // L7 out:          [c0..c64 | 5 pad]
  __shared__ float scLog[64];     // write-once: L3:0..31 L4:32..47 L5:48..55 L6:56..59 L7:60..61
  __shared__ float red[8];        // [0..3] per-wave sum(w); [4..7] per-wave sum(S)

  const int t  = threadIdx.x;
  const int wv = t >> 6;
  const int s  = blockIdx.x;

  // ---------- phase 1: leaf ESP deg<=6, all 10 loads batched up front (nt) ----------
  const f32x4* xv = (const f32x4*)(x + (size_t)s * NC);     // 2500 float4
  f32x4 buf[10];
#pragma unroll
  for (int it = 0; it < 9; ++it) buf[it] = __builtin_nontemporal_load(&xv[t + it * 256]);
  buf[9] = (f32x4){-1e30f, -1e30f, -1e30f, -1e30f};          // exp -> 0
  if (t < 196) buf[9] = __builtin_nontemporal_load(&xv[2304 + t]);   // 2304..2499

  float c0 = 1.f, c1 = 0.f, c2 = 0.f, c3 = 0.f, c4 = 0.f, c5 = 0.f, c6 = 0.f;
  float sw = 0.f;
#pragma unroll
  for (int it = 0; it < 10; ++it) {
    const f32x4 v = buf[it];
#pragma unroll
    for (int q = 0; q < 4; ++q) {
      const float xval = q == 0 ? v.x : q == 1 ? v.y : q == 2 ? v.z : v.w;
      const float w = __expf(xval);
      sw += w;
      c6 = fmaf(w, c5, c6);
      c5 = fmaf(w, c4, c5);
      c4 = fmaf(w, c3, c4);
      c3 = fmaf(w, c2, c3);
      c2 = fmaf(w, c1, c2);
      c1 = fmaf(w, c0, c1);   // c0 stays 1 (untilted leaf is f32-safe)
    }
  }

  // ---------- tilt tau = ln(wbar*(NC-K)/K) ----------
#pragma unroll
  for (int m = 1; m < 64; m <<= 1) sw += __shfl_xor(sw, m);
  if ((t & 63) == 0) red[wv] = sw;
  __syncthreads();                                   // barrier 1
  const float wsum = red[0] + red[1] + red[2] + red[3];
  const float tau = __logf(wsum * ((float)(NC - KSEL) / ((float)KSEL * (float)NC)));

  // tilt + leaf max-normalize (registers)
  {
    const float f1 = __expf(-tau);
    const float f2 = f1 * f1, f3 = f2 * f1, f4v = f2 * f2, f5 = f4v * f1, f6 = f4v * f2;
    c1 *= f1; c2 *= f2; c3 *= f3; c4 *= f4v; c5 *= f5; c6 *= f6;
  }
  {
    const float mx = fmaxf(fmaxf(fmaxf(c0, c1), fmaxf(c2, c3)), fmaxf(fmaxf(c4, c5), c6));
    const float invm = 1.f / mx;
    c0 *= invm; c1 *= invm; c2 *= invm; c3 *= invm; c4 *= invm; c5 *= invm; c6 *= invm;
    float Sr = __logf(mx);
#pragma unroll
    for (int m = 1; m < 64; m <<= 1) Sr += __shfl_xor(Sr, m);
    if ((t & 63) == 0) red[4 + wv] = Sr;             // read by L8 after barrier 2/3
  }

  // ---------- RL1: pair merge via shfl (deg 7) ----------
  const float q0 = __shfl_xor(c0, 1), q1 = __shfl_xor(c1, 1), q2 = __shfl_xor(c2, 1),
              q3 = __shfl_xor(c3, 1), q4 = __shfl_xor(c4, 1), q5 = __shfl_xor(c5, 1),
              q6 = __shfl_xor(c6, 1);
  const float e0 = c0 * q0;
  const float e1 = fmaf(c1, q0, c0 * q1);
  const float e2 = fmaf(c2, q0, fmaf(c1, q1, c0 * q2));
  const float e3 = fmaf(c3, q0, fmaf(c2, q1, fmaf(c1, q2, c0 * q3)));
  const float e4 = fmaf(c4, q0, fmaf(c3, q1, fmaf(c2, q2, fmaf(c1, q3, c0 * q4))));
  const float e5 = fmaf(c5, q0, fmaf(c4, q1, fmaf(c3, q2, fmaf(c2, q3, fmaf(c1, q4, c0 * q5)))));
  const float e6 = fmaf(c6, q0, fmaf(c5, q1, fmaf(c4, q2, fmaf(c3, q3, fmaf(c2, q4, fmaf(c1, q5, c0 * q6))))));
  const float e7 = fmaf(c6, q1, fmaf(c5, q2, fmaf(c4, q3, fmaf(c3, q4, fmaf(c2, q5, c1 * q6)))));

  // ---------- RL2: 4-leaf merge via shfl (deg 11) ----------
  const float f0 = __shfl_xor(e0, 2), f1 = __shfl_xor(e1, 2), f2 = __shfl_xor(e2, 2),
              f3 = __shfl_xor(e3, 2), f4 = __shfl_xor(e4, 2), f5 = __shfl_xor(e5, 2),
              f6 = __shfl_xor(e6, 2), f7 = __shfl_xor(e7, 2);
  const float g0 = e0 * f0;
  const float g1 = fmaf(e1, f0, e0 * f1);
  const float g2 = fmaf(e2, f0, fmaf(e1, f1, e0 * f2));
  const float g3 = fmaf(e3, f0, fmaf(e2, f1, fmaf(e1, f2, e0 * f3)));
  const float g4 = fmaf(e4, f0, fmaf(e3, f1, fmaf(e2, f2, fmaf(e1, f3, e0 * f4))));
  const float g5 = fmaf(e5, f0, fmaf(e4, f1, fmaf(e3, f2, fmaf(e2, f3, fmaf(e1, f4, e0 * f5)))));
  const float g6 = fmaf(e6, f0, fmaf(e5, f1, fmaf(e4, f2, fmaf(e3, f3, fmaf(e2, f4, fmaf(e1, f5, e0 * f6))))));
  const float g7 = fmaf(e7, f0, fmaf(e6, f1, fmaf(e5, f2, fmaf(e4, f3, fmaf(e3, f4, fmaf(e2, f5, fmaf(e1, f6, e0 * f7)))))));
  const float g8 = fmaf(e7, f1, fmaf(e6, f2, fmaf(e5, f3, fmaf(e4, f4, fmaf(e3, f5, fmaf(e2, f6, e1 * f7))))));
  const float g9 = fmaf(e7, f2, fmaf(e6, f3, fmaf(e5, f4, fmaf(e4, f5, fmaf(e3, f6, e2 * f7)))));
  const float g10 = fmaf(e7, f3, fmaf(e6, f4, fmaf(e5, f5, fmaf(e4, f6, e3 * f7))));
  const float g11 = fmaf(e7, f4, fmaf(e6, f5, fmaf(e5, f6, e4 * f7)));

  // store W2 row (quad q = t>>2): [11 z | g0..g11 | 5 z], 7 aligned float4
  if ((t & 3) == 0) {
    float* row = W2 + (t >> 2) * 28;
    *(float4*)(row)      = make_float4(0.f, 0.f, 0.f, 0.f);
    *(float4*)(row + 4)  = make_float4(0.f, 0.f, 0.f, 0.f);
    *(float4*)(row + 8)  = make_float4(0.f, 0.f, 0.f, g0);
    *(float4*)(row + 12) = make_float4(g1, g2, g3, g4);
    *(float4*)(row + 16) = make_float4(g5, g6, g7, g8);
    *(float4*)(row + 20) = make_float4(g9, g10, g11, 0.f);
    *(float4*)(row + 24) = make_float4(0.f, 0.f, 0.f, 0.f);
  }
  // L3 reads only rows written by its own wave -> no barrier (lgkmcnt ordering)

  // ---------- L3: 32 merges x 8 lanes; in deg 11 -> keep 16 ----------
  {
    const int m = t >> 3, r = t & 7;
    const float* A = W2 + (2 * m) * 28;
    const float* B = W2 + (2 * m + 1) * 28;
    float o0 = 0.f, o1 = 0.f, o2 = 0.f;            // degrees r, r+8, 16
#pragma unroll
    for (int i = 0; i <= 11; ++i) {
      const float ai = A[11 + i];
      o0 = fmaf(ai, B[11 + r - i], o0);            // idx 0..18
      o1 = fmaf(ai, B[19 + r - i], o1);            // idx 8..26
      o2 = fmaf(ai, B[27 - i], o2);                // idx 16..27 (same for all lanes)
    }
    float mx = fmaxf(fmaxf(o0, o1), o2);
    mx = fmaxf(mx, __shfl_xor(mx, 1));
    mx = fmaxf(mx, __shfl_xor(mx, 2));
    mx = fmaxf(mx, __shfl_xor(mx, 4));
    const float inv = 1.f / mx;
    float* O = W3 + m * 37;                         // [16 z | c0..c16 | 4 z]
    O[16 + r] = o0 * inv;
    O[24 + r] = o1 * inv;
    if (r == 0) { O[32] = o2 * inv; scLog[m] = __logf(mx); }
    O[r] = 0.f; O[8 + r] = 0.f;
    if (r < 4) O[33 + r] = 0.f;
  }

  // ---------- L4: 16 merges x 16 lanes; in deg 16 -> keep 20 ----------
  {
    const int m = t >> 4, r = t & 15;
    const float* A = W3 + (2 * m) * 37;
    const float* B = W3 + (2 * m + 1) * 37;
    float o0 = 0.f, o1 = 0.f;                       // degrees r, r+16 (r<5)
#pragma unroll
    for (int i = 0; i <= 16; ++i) {
      const float ai = A[16 + i];
      o0 = fmaf(ai, B[16 + r - i], o0);             // idx 0..31
      o1 = fmaf(ai, B[32 + r - i], o1);             // valid only r<5
    }
    if (r >= 5) o1 = 0.f;                           // discard garbage lanes
    float mx = fmaxf(o0, o1);
    mx = fmaxf(mx, __shfl_xor(mx, 1));
    mx = fmaxf(mx, __shfl_xor(mx, 2));
    mx = fmaxf(mx, __shfl_xor(mx, 4));
    mx = fmaxf(mx, __shfl_xor(mx, 8));
    const float inv = 1.f / mx;
    float* O = W4 + m * 53;                         // [20 z | c0..c20 | 12 z]
    O[20 + r] = o0 * inv;
    if (r < 5) O[36 + r] = o1 * inv;
    if (r == 0) scLog[32 + m] = __logf(mx);
    O[r] = 0.f;
    if (r < 4) O[16 + r] = 0.f;
    if (r < 12) O[41 + r] = 0.f;
  }

  // ---------- L5: 8 merges x 32 lanes; in deg 20 -> keep 32 ----------
  {
    const int m = t >> 5, p = t & 31;
    const float* A = W4 + (2 * m) * 53;
    const float* B = W4 + (2 * m + 1) * 53;
    float o0 = 0.f, o1 = 0.f;                       // degrees p, 32
#pragma unroll
    for (int i = 0; i <= 20; ++i) {
      const float ai = A[20 + i];
      o0 = fmaf(ai, B[20 + p - i], o0);             // idx 0..51
      o1 = fmaf(ai, B[52 - i], o1);                 // idx 31..52 (uniform)
    }
    float mx = fmaxf(o0, o1);
    mx = fmaxf(mx, __shfl_xor(mx, 1));
    mx = fmaxf(mx, __shfl_xor(mx, 2));
    mx = fmaxf(mx, __shfl_xor(mx, 4));
    mx = fmaxf(mx, __shfl_xor(mx, 8));
    mx = fmaxf(mx, __shfl_xor(mx, 16));
    const float inv = 1.f / mx;
    float* O = W5 + m * 77;                         // [32 z | c0..c32 | 12 z]
    O[32 + p] = o0 * inv;
    if (p == 0) { O[64] = o1 * inv; scLog[48 + m] = __logf(mx); }
    O[p] = 0.f;
    if (p < 12) O[65 + p] = 0.f;
  }

  // ---------- L6: 4 merges x 64 lanes; in deg 32 -> keep 44 ----------
  {
    const int p = t & 63;
    const float* A = W5 + (2 * wv) * 77;
    const float* B = W5 + (2 * wv + 1) * 77;
    float o0 = 0.f;                                 // degree p (<45)
#pragma unroll
    for (int i = 0; i <= 32; ++i) {
      const float ai = A[32 + i];
      o0 = fmaf(ai, B[32 + p - i], o0);             // idx 0..107 (masked below)
    }
    if (p >= 45) o0 = 0.f;
    float mx = o0;
#pragma unroll
    for (int msk = 1; msk < 64; msk <<= 1) mx = fmaxf(mx, __shfl_xor(mx, msk));
    const float inv = 1.f / mx;
    float* O = W6 + wv * 109;                       // [44 z | c0..c44 | 20 z]
    if (p < 45) O[44 + p] = o0 * inv;
    if (p == 0) scLog[56 + wv] = __logf(mx);
    if (p < 44) O[p] = 0.f;
    if (p < 20) O[89 + p] = 0.f;
  }
  __syncthreads();                                   // barrier 2 (cross-wave W6)

  // ---------- L7: 2 merges, waves 0,1; in deg 44 -> keep 64 ----------
  if (t < 128) {
    const int p = t & 63;
    const float* A = W6 + (2 * wv) * 109;
    const float* B = W6 + (2 * wv + 1) * 109;
    float o0 = 0.f, o1 = 0.f;                        // degrees p, 64
#pragma unroll
    for (int i = 0; i <= 44; ++i) {
      const float ai = A[44 + i];
      o0 = fmaf(ai, B[44 + p - i], o0);              // idx 0..107
      o1 = fmaf(ai, B[108 - i], o1);                 // idx 64..108 (uniform)
    }
    float mx = fmaxf(o0, o1);
#pragma unroll
    for (int msk = 1; msk < 64; msk <<= 1) mx = fmaxf(mx, __shfl_xor(mx, msk));
    const float inv = 1.f / mx;
    float* O = W7 + wv * 70;                         // [c0..c64 | pad]
    O[p] = o0 * inv;
    if (p == 0) { O[64] = o1 * inv; scLog[60 + wv] = __logf(mx); }
  }
  __syncthreads();                                   // barrier 3 (cross-wave W7)

  // ---------- L8: final degrees 63,64 + output ----------
  if (t < 64) {
    const float* A = W7;
    const float* B = W7 + 70;
    const float a = A[t];
    float v63 = a * B[63 - t];
    float v64 = a * B[64 - t];
    float ee = (t < 62) ? scLog[t] : 0.f;
#pragma unroll
    for (int msk = 1; msk < 64; msk <<= 1) {
      v63 += __shfl_xor(v63, msk);
      v64 += __shfl_xor(v64, msk);
      ee  += __shfl_xor(ee, msk);
    }
    if (t == 0) {
      v64 = fmaf(A[64], B[0], v64);
      const float Ssum = red[4] + red[5] + red[6] + red[7] + ee;
      out[s]      = __logf(v63) + Ssum + 63.f * tau;
      out[NS + s] = __logf(v64) + Ssum + 64.f * tau;
    }
  }
}

extern "C" void kernel_launch(void* const* d_in, const int* in_sizes, int n_in,
                              void* d_out, int out_size, void* d_ws, size_t ws_size,
                              hipStream_t stream) {
  const float* x = (const float*)d_in[0];
  float* out = (float*)d_out;
  (void)in_sizes; (void)n_in; (void)d_ws; (void)ws_size; (void)out_size;
  logesp_kernel<<<NS, 256, 0, stream>>>(x, out);
}